// Round 8
// baseline (106.260 us; speedup 1.0000x reference)
//
#include <hip/hip_runtime.h>

// Problem: T=4096, C=64, D=512.
// out[t,c,d] = exp(rowsum(W)[c] * colsum(W)[d]) / D   (independent of t and x)
//
// Fused single kernel. Stream-count curve measured (256-thr blocks):
// 2048 blk = 129 us, 512 blk = 112, 256 blk = 97. Still improving at the low
// end -> this probe halves streams again: 256 blocks x 128 THREADS
// (2 waves/CU, 32768 store streams, 1024 NT stores each at 512 KB stride).
// Stride (32768 float4) is a multiple of the remap tile (8192 float4), so the
// per-thread source value stays loop-invariant.

#define T_DIM 4096
#define C_DIM 64
#define D_DIM 512

typedef float f32x4 __attribute__((ext_vector_type(4)));

__global__ __launch_bounds__(128) void fused_broadcast_kernel(
    const float* __restrict__ w, f32x4* __restrict__ out) {
    const int t = threadIdx.x;              // 0..127
    const unsigned b = blockIdx.x;          // 0..255
    const unsigned tid = b * 128u + t;      // 0..32767

    // ---- mapping ----
    // source float4 idx = tid & 8191; float idx s = 4*(tid&8191)+k.
    // c = s>>9 = b & 63 (uniform per block); d = 4t + k (independent of b).
    const int c = (int)(b & 63u);

    // ---- row sum rs[c]: 128 threads x 4 elements, 2-wave reduce ----
    float p0 = (w[c * D_DIM + t]       + w[c * D_DIM + 128 + t]) +
               (w[c * D_DIM + 256 + t] + w[c * D_DIM + 384 + t]);
    #pragma unroll
    for (int off = 32; off > 0; off >>= 1) {
        p0 += __shfl_down(p0, off);
    }
    __shared__ float red[2];                // 2 waves
    const int wave = t >> 6, lane = t & 63;
    if (lane == 0) red[wave] = p0;
    __syncthreads();
    const float rs = red[0] + red[1];

    // ---- col sums cs[4t..4t+3]: 64 coalesced f32x4 loads (L2-hot) ----
    const f32x4* col = (const f32x4*)(w + 4 * t);   // row stride = 128 f32x4
    f32x4 a0 = {0.f, 0.f, 0.f, 0.f}, a1 = a0, a2 = a0, a3 = a0;
    #pragma unroll
    for (int r = 0; r < C_DIM; r += 4) {
        a0 += col[(r + 0) * (D_DIM / 4)];
        a1 += col[(r + 1) * (D_DIM / 4)];
        a2 += col[(r + 2) * (D_DIM / 4)];
        a3 += col[(r + 3) * (D_DIM / 4)];
    }
    const f32x4 cs4 = (a0 + a1) + (a2 + a3);

    // ---- remap value (det = D for zero input colsums) ----
    const float inv_det = 1.0f / (float)D_DIM;
    f32x4 v;
    v.x = expf(rs * cs4.x) * inv_det;
    v.y = expf(rs * cs4.y) * inv_det;
    v.z = expf(rs * cs4.z) * inv_det;
    v.w = expf(rs * cs4.w) * inv_det;

    // ---- stream 1024 NT stores, 512 KB grid stride ----
    const unsigned STRIDE = 256u * 128u;     // 32768 float4 = mult of 8192
    const int ITERS = (T_DIM * C_DIM * D_DIM / 4) / STRIDE;  // 1024
    f32x4* p = out + tid;
    #pragma unroll 8
    for (int i = 0; i < ITERS; ++i) {
        __builtin_nontemporal_store(v, p);
        p += STRIDE;
    }
}

extern "C" void kernel_launch(void* const* d_in, const int* in_sizes, int n_in,
                              void* d_out, int out_size, void* d_ws, size_t ws_size,
                              hipStream_t stream) {
    // d_in[0] = x (unused by the math), d_in[1] = weight (64 x 512 f32)
    const float* weight = (const float*)d_in[1];
    fused_broadcast_kernel<<<256, 128, 0, stream>>>(weight, (f32x4*)d_out);
}

// Round 9
// 104.710 us; speedup vs baseline: 1.0148x; 1.0148x over previous
//
#include <hip/hip_runtime.h>

// Problem: T=4096, C=64, D=512.
// out[t,c,d] = exp(rowsum(W)[c] * colsum(W)[d]) / D   (independent of t and x)
//
// Fused single kernel. Measured stream-count curve (total threads):
// 32K=106us, 64K=97 (min), 131K=112, 524K=129 -> keep 256 blocks x 256 thr.
// This round: longer contiguous runs per block. Each thread now owns FOUR
// loop-invariant source float4s and writes 64 B/lane per iteration:
//   out4[i*262144 + b*1024 + wave*256 + q*64 + lane],  q = 0..3
// -> each store instruction is 1 KB lane-contiguous, wave covers 4 KB/iter,
//    block covers 16 KB contiguous per iter (vs 4 KB before), 128 iters at
//    4 MB stride. 262144 % 8192 == 0 keeps sources loop-invariant.
// Prologue builds cs[512] + rs[64] in LDS cooperatively (w is 128 KiB,
// L2-hot), then: c = (b&7)*8 + wave*2 + (q>=2), d-group = lane (q even) or
// lane+64 (q odd).

#define T_DIM 4096
#define C_DIM 64
#define D_DIM 512

typedef float f32x4 __attribute__((ext_vector_type(4)));
typedef float f32x2 __attribute__((ext_vector_type(2)));

__global__ __launch_bounds__(256) void fused_broadcast_kernel(
    const float* __restrict__ w, f32x4* __restrict__ out) {
    const int t = threadIdx.x;              // 0..255
    const unsigned b = blockIdx.x;          // 0..255
    const int wv = t >> 6, l = t & 63;

    __shared__ f32x2 cs2[D_DIM / 2];        // cs[512] as 256 f32x2
    __shared__ float rs[C_DIM];

    // ---- col sums: thread t owns columns {2t, 2t+1} (coalesced f32x2) ----
    {
        const f32x2* w2 = (const f32x2*)w;  // 64 rows x 256 f32x2
        f32x2 a0 = {0.f, 0.f}, a1 = a0, a2 = a0, a3 = a0;
        #pragma unroll
        for (int r = 0; r < C_DIM; r += 4) {
            a0 += w2[(r + 0) * 256 + t];
            a1 += w2[(r + 1) * 256 + t];
            a2 += w2[(r + 2) * 256 + t];
            a3 += w2[(r + 3) * 256 + t];
        }
        cs2[t] = (a0 + a1) + (a2 + a3);
    }
    // ---- row sums: threads 0..63 each reduce one row (f32x4, 4 chains) ----
    if (t < C_DIM) {
        const f32x4* wr = (const f32x4*)(w + t * D_DIM);  // 128 f32x4
        f32x4 a0 = {0.f, 0.f, 0.f, 0.f}, a1 = a0, a2 = a0, a3 = a0;
        #pragma unroll
        for (int i = 0; i < 128; i += 4) {
            a0 += wr[i + 0];
            a1 += wr[i + 1];
            a2 += wr[i + 2];
            a3 += wr[i + 3];
        }
        f32x4 s = (a0 + a1) + (a2 + a3);
        rs[t] = (s.x + s.y) + (s.z + s.w);
    }
    __syncthreads();

    // ---- gather this thread's 4 source values ----
    const int c0 = (int)(b & 7u) * 8 + wv * 2;  // rows for q=0,1 / q=2,3
    const float r0 = rs[c0], r1 = rs[c0 + 1];
    const f32x4* cs4 = (const f32x4*)cs2;       // 128 f32x4
    const f32x4 csA = cs4[l], csB = cs4[64 + l];

    const float inv_det = 1.0f / (float)D_DIM;  // det = D for zero colsums
    auto remap4 = [inv_det](float r, f32x4 c) {
        f32x4 o;
        o.x = expf(r * c.x) * inv_det;
        o.y = expf(r * c.y) * inv_det;
        o.z = expf(r * c.z) * inv_det;
        o.w = expf(r * c.w) * inv_det;
        return o;
    };
    const f32x4 v0 = remap4(r0, csA);  // q=0
    const f32x4 v1 = remap4(r0, csB);  // q=1
    const f32x4 v2 = remap4(r1, csA);  // q=2
    const f32x4 v3 = remap4(r1, csB);  // q=3

    // ---- stream: 128 iters x 4 KB per wave, block-contiguous 16 KB ----
    const unsigned STRIDE = 262144u;    // 65536 threads * 4 f32x4; %8192==0
    f32x4* p = out + (size_t)b * 1024 + (size_t)wv * 256 + l;
    #pragma unroll 4
    for (int i = 0; i < 128; ++i) {
        __builtin_nontemporal_store(v0, p);
        __builtin_nontemporal_store(v1, p + 64);
        __builtin_nontemporal_store(v2, p + 128);
        __builtin_nontemporal_store(v3, p + 192);
        p += STRIDE;
    }
}

extern "C" void kernel_launch(void* const* d_in, const int* in_sizes, int n_in,
                              void* d_out, int out_size, void* d_ws, size_t ws_size,
                              hipStream_t stream) {
    // d_in[0] = x (unused by the math), d_in[1] = weight (64 x 512 f32)
    const float* weight = (const float*)d_in[1];
    fused_broadcast_kernel<<<256, 256, 0, stream>>>(weight, (f32x4*)d_out);
}

// Round 10
// 93.161 us; speedup vs baseline: 1.1406x; 1.1240x over previous
//
#include <hip/hip_runtime.h>

// Problem: T=4096, C=64, D=512.
// out[t,c,d] = exp(rowsum(W)[c] * colsum(W)[d]) / D   (independent of t and x)
//
// Fused single kernel. Store loop = the measured optimum (R5/R7, 97.1 us):
// 256 blocks x 256 threads (1 block/CU), each thread 512 NT float4 stores at
// 1 MB grid stride; stride (65536 f32x4) is a multiple of the remap tile
// (8192 f32x4) so the source value is loop-invariant.
//
// This round: PROLOGUE DIET. Col-sums computed cooperatively -- each thread
// sums a 32-row half of one f32x4 column strip (32 coalesced loads, 4x8
// chains), halves combined via LDS. Per-thread prologue loads 66 -> 34,
// dependent add chain 16 -> 8. Store loop untouched.

#define T_DIM 4096
#define C_DIM 64
#define D_DIM 512

typedef float f32x4 __attribute__((ext_vector_type(4)));

__global__ __launch_bounds__(256) void fused_broadcast_kernel(
    const float* __restrict__ w, f32x4* __restrict__ out) {
    const int t = threadIdx.x;              // 0..255
    const unsigned b = blockIdx.x;          // 0..255
    const unsigned tid = b * 256u + t;      // 0..65535

    __shared__ f32x4 part[2][128];          // col-sum halves, 4 KB
    __shared__ float red[8];                // rowsum wave partials

    // ---- cooperative col sums: strip g = t&127, rows h*32..h*32+31 ----
    {
        const f32x4* w4 = (const f32x4*)w;  // 64 rows x 128 f32x4
        const int g = t & 127, h = t >> 7;
        const f32x4* p = w4 + (size_t)(h * 32) * 128 + g;
        f32x4 a0 = {0.f, 0.f, 0.f, 0.f}, a1 = a0, a2 = a0, a3 = a0;
        #pragma unroll
        for (int r = 0; r < 32; r += 4) {
            a0 += p[(r + 0) * 128];
            a1 += p[(r + 1) * 128];
            a2 += p[(r + 2) * 128];
            a3 += p[(r + 3) * 128];
        }
        part[h][g] = (a0 + a1) + (a2 + a3);
    }

    // ---- row sums for this block's two rows: block reduce via shfl ----
    const int c0 = (int)((b & 31u) * 2u);
    const int c1 = c0 + 1;
    {
        float p0 = w[c0 * D_DIM + t] + w[c0 * D_DIM + 256 + t];
        float p1 = w[c1 * D_DIM + t] + w[c1 * D_DIM + 256 + t];
        #pragma unroll
        for (int off = 32; off > 0; off >>= 1) {
            p0 += __shfl_down(p0, off);
            p1 += __shfl_down(p1, off);
        }
        const int wave = t >> 6, lane = t & 63;
        if (lane == 0) { red[wave * 2] = p0; red[wave * 2 + 1] = p1; }
    }
    __syncthreads();

    const float rs0 = (red[0] + red[2]) + (red[4] + red[6]);
    const float rs1 = (red[1] + red[3]) + (red[5] + red[7]);
    const float rs = (t >> 7) ? rs1 : rs0;

    // cs for this thread's d-group: f32x4 index (4t)/4 & 127 = t & 127.
    // part[0][x] + part[1][x]; threads t and t+128 read the same address ->
    // 2-way broadcast, conflict-free.
    const f32x4 cs4 = part[0][t & 127] + part[1][t & 127];

    // ---- remap value (det = D for zero input colsums) ----
    const float inv_det = 1.0f / (float)D_DIM;
    f32x4 v;
    v.x = expf(rs * cs4.x) * inv_det;
    v.y = expf(rs * cs4.y) * inv_det;
    v.z = expf(rs * cs4.z) * inv_det;
    v.w = expf(rs * cs4.w) * inv_det;

    // ---- stream 512 NT stores, 1 MB grid stride (unchanged from 97 us) ----
    const unsigned STRIDE = 256u * 256u;     // 65536 float4 = mult of 8192
    const int ITERS = (T_DIM * C_DIM * D_DIM / 4) / STRIDE;  // 512
    f32x4* p = out + tid;
    #pragma unroll 4
    for (int i = 0; i < ITERS; ++i) {
        __builtin_nontemporal_store(v, p);
        p += STRIDE;
    }
}

extern "C" void kernel_launch(void* const* d_in, const int* in_sizes, int n_in,
                              void* d_out, int out_size, void* d_ws, size_t ws_size,
                              hipStream_t stream) {
    // d_in[0] = x (unused by the math), d_in[1] = weight (64 x 512 f32)
    const float* weight = (const float*)d_in[1];
    fused_broadcast_kernel<<<256, 256, 0, stream>>>(weight, (f32x4*)d_out);
}